// Round 1
// baseline (1373.242 us; speedup 1.0000x reference)
//
#include <hip/hip_runtime.h>

#define D 128

// ---------------- scatter: one wave (64 lanes) per edge ----------------
__global__ void __launch_bounds__(256) scatter_kernel(
    const float* __restrict__ xsrc, const int* __restrict__ ei, int nedge,
    float* __restrict__ agg, float* __restrict__ cnt) {
  int gtid = blockIdx.x * 256 + threadIdx.x;
  int e = gtid >> 6;
  int lane = threadIdx.x & 63;
  if (e >= nedge) return;
  int src = ei[e];           // ei[0][e]
  int dst = ei[nedge + e];   // ei[1][e]
  const float* xr = xsrc + (size_t)src * D;
  float v0 = xr[lane];
  float v1 = xr[lane + 64];
  float* ar = agg + (size_t)dst * D;
  unsafeAtomicAdd(ar + lane, v0);
  unsafeAtomicAdd(ar + lane + 64, v1);
  if (lane == 0) unsafeAtomicAdd(cnt + dst, 1.0f);
}

// ---------------- cnt -> 1/max(cnt,1) in place ----------------
__global__ void invcnt_kernel(float* __restrict__ c0, float* __restrict__ c1,
                              float* __restrict__ c2, int n) {
  int i = blockIdx.x * blockDim.x + threadIdx.x;
  if (i >= n) return;
  c0[i] = 1.0f / fmaxf(c0[i], 1.0f);
  c1[i] = 1.0f / fmaxf(c1[i], 1.0f);
  c2[i] = 1.0f / fmaxf(c2[i], 1.0f);
}

// ---------------- build combined transposed weights + biases ----------------
// Wt_item[k][n], k<128: Wl_rates[n][k]; k in [128,256): Wr_rates[n][k-128]
// Wt_user[k][n], k<128: .5*Wl_rev[n][k]; [128,256): .5*Wl_fol; [256,384): .5*(Wr_rev+Wr_fol)
__global__ void prep_kernel(
    const float* __restrict__ Wl_rates, const float* __restrict__ Wr_rates, const float* __restrict__ bl_rates,
    const float* __restrict__ Wl_rev, const float* __restrict__ Wr_rev, const float* __restrict__ bl_rev,
    const float* __restrict__ Wl_fol, const float* __restrict__ Wr_fol, const float* __restrict__ bl_fol,
    float* __restrict__ Wt_item, float* __restrict__ Wt_user,
    float* __restrict__ b_item, float* __restrict__ b_user) {
  int idx = blockIdx.x * 256 + threadIdx.x;
  if (idx >= 384 * 128) return;
  int n = idx & 127;
  int k = idx >> 7;
  if (k < 256) {
    float v = (k < 128) ? Wl_rates[n * 128 + k] : Wr_rates[n * 128 + (k - 128)];
    Wt_item[k * 128 + n] = v;
  }
  float v;
  if (k < 128)      v = 0.5f * Wl_rev[n * 128 + k];
  else if (k < 256) v = 0.5f * Wl_fol[n * 128 + (k - 128)];
  else              v = 0.5f * (Wr_rev[n * 128 + (k - 256)] + Wr_fol[n * 128 + (k - 256)]);
  Wt_user[k * 128 + n] = v;
  if (idx < 128) {
    b_item[idx] = bl_rates[idx];
    b_user[idx] = 0.5f * (bl_rev[idx] + bl_fol[idx]);
  }
}

// ---------------- fp32 GEMM: out[M x 128] = A[M x K] * Wt[K x 128] + bias ----
// A is a virtual concat of up to 3 [M x 128] buffers, each optionally scaled
// per-row by inv[] (mean division folded into staging).
struct Srcs {
  const float* s0; const float* i0;
  const float* s1; const float* i1;
  const float* s2; const float* i2;
};

__global__ void __launch_bounds__(256) gemm_kernel(
    Srcs S, int nbuf, const float* __restrict__ Wt, const float* __restrict__ bias,
    float* __restrict__ out, int M) {
  __shared__ float Asub[64 * 64];    // 16 KB  [row][k]
  __shared__ float Wsub[64 * 128];   // 32 KB  [k][n]
  const int tid = threadIdx.x;
  const int tx = tid & 31;           // col group: cols tx*4 .. tx*4+3
  const int ty = tid >> 5;           // row group: rows ty*8 .. ty*8+7
  const int m0 = blockIdx.x * 64;

  float acc[8][4];
#pragma unroll
  for (int i = 0; i < 8; i++)
#pragma unroll
    for (int j = 0; j < 4; j++) acc[i][j] = 0.0f;

  const float* sbuf[3] = {S.s0, S.s1, S.s2};
  const float* ibuf[3] = {S.i0, S.i1, S.i2};
  const int nchunks = nbuf * 2;      // 64-wide K chunks

  for (int c = 0; c < nchunks; c++) {
    const int kk0 = c * 64;
    const float* sp = sbuf[c >> 1];
    const float* ip = ibuf[c >> 1];
    const int coff = (c & 1) * 64;
    // stage A: 64 rows x 64 k
#pragma unroll
    for (int t = 0; t < 16; t++) {
      int lin = t * 256 + tid;       // row*64 + kk
      int row = lin >> 6, kk = lin & 63;
      int m = m0 + row;
      float v = 0.0f;
      if (m < M) {
        v = sp[(size_t)m * D + coff + kk];
        if (ip) v *= ip[m];
      }
      Asub[lin] = v;
    }
    // stage Wt chunk: 64 k x 128 n
#pragma unroll
    for (int t = 0; t < 32; t++) {
      int lin = t * 256 + tid;       // kk*128 + n
      Wsub[lin] = Wt[(size_t)kk0 * 128 + lin];
    }
    __syncthreads();
#pragma unroll
    for (int k4 = 0; k4 < 16; k4++) {
      const int k = k4 * 4;
      float4 w0 = *(const float4*)&Wsub[(k + 0) * 128 + tx * 4];
      float4 w1 = *(const float4*)&Wsub[(k + 1) * 128 + tx * 4];
      float4 w2 = *(const float4*)&Wsub[(k + 2) * 128 + tx * 4];
      float4 w3 = *(const float4*)&Wsub[(k + 3) * 128 + tx * 4];
#pragma unroll
      for (int i = 0; i < 8; i++) {
        float4 a = *(const float4*)&Asub[(ty * 8 + i) * 64 + k];
        acc[i][0] += a.x * w0.x + a.y * w1.x + a.z * w2.x + a.w * w3.x;
        acc[i][1] += a.x * w0.y + a.y * w1.y + a.z * w2.y + a.w * w3.y;
        acc[i][2] += a.x * w0.z + a.y * w1.z + a.z * w2.z + a.w * w3.z;
        acc[i][3] += a.x * w0.w + a.y * w1.w + a.z * w2.w + a.w * w3.w;
      }
    }
    __syncthreads();
  }

  float4 bv = *(const float4*)&bias[tx * 4];
#pragma unroll
  for (int i = 0; i < 8; i++) {
    int m = m0 + ty * 8 + i;
    if (m < M) {
      float4 o;
      o.x = acc[i][0] + bv.x;
      o.y = acc[i][1] + bv.y;
      o.z = acc[i][2] + bv.z;
      o.w = acc[i][3] + bv.w;
      *(float4*)&out[(size_t)m * D + tx * 4] = o;
    }
  }
}

extern "C" void kernel_launch(void* const* d_in, const int* in_sizes, int n_in,
                              void* d_out, int out_size, void* d_ws, size_t ws_size,
                              hipStream_t stream) {
  const float* x_user   = (const float*)d_in[0];
  const float* x_item   = (const float*)d_in[1];
  const int*   ei_rates = (const int*)d_in[2];
  const int*   ei_rev   = (const int*)d_in[3];
  const int*   ei_fol   = (const int*)d_in[4];
  const float* Wl_rates = (const float*)d_in[5];
  const float* bl_rates = (const float*)d_in[6];
  const float* Wr_rates = (const float*)d_in[7];
  const float* Wl_rev   = (const float*)d_in[8];
  const float* bl_rev   = (const float*)d_in[9];
  const float* Wr_rev   = (const float*)d_in[10];
  const float* Wl_fol   = (const float*)d_in[11];
  const float* bl_fol   = (const float*)d_in[12];
  const float* Wr_fol   = (const float*)d_in[13];

  const int NU = in_sizes[0] / D;       // 50000
  const int NI = in_sizes[1] / D;       // 50000
  const int E_rates = in_sizes[2] / 2;  // 600000
  const int E_rev   = in_sizes[3] / 2;
  const int E_fol   = in_sizes[4] / 2;

  float* ws = (float*)d_ws;
  size_t off = 0;
  float* agg_rates = ws + off; off += (size_t)NI * D;
  float* agg_rev   = ws + off; off += (size_t)NU * D;
  float* agg_fol   = ws + off; off += (size_t)NU * D;
  float* cnt_rates = ws + off; off += NI;
  float* cnt_rev   = ws + off; off += NU;
  float* cnt_fol   = ws + off; off += NU;
  const size_t zero_floats = off;       // zero agg + cnt regions
  float* Wt_item   = ws + off; off += 256 * 128;
  float* Wt_user   = ws + off; off += 384 * 128;
  float* b_item    = ws + off; off += 128;
  float* b_user    = ws + off; off += 128;

  hipMemsetAsync(d_ws, 0, zero_floats * sizeof(float), stream);
  prep_kernel<<<192, 256, 0, stream>>>(Wl_rates, Wr_rates, bl_rates,
                                       Wl_rev, Wr_rev, bl_rev,
                                       Wl_fol, Wr_fol, bl_fol,
                                       Wt_item, Wt_user, b_item, b_user);

  auto sblocks = [](int e) { return (e * 64 + 255) / 256; };
  scatter_kernel<<<sblocks(E_rates), 256, 0, stream>>>(x_user, ei_rates, E_rates, agg_rates, cnt_rates);
  scatter_kernel<<<sblocks(E_rev),   256, 0, stream>>>(x_item, ei_rev,   E_rev,   agg_rev,   cnt_rev);
  scatter_kernel<<<sblocks(E_fol),   256, 0, stream>>>(x_user, ei_fol,   E_fol,   agg_fol,   cnt_fol);
  invcnt_kernel<<<(NU + 255) / 256, 256, 0, stream>>>(cnt_rates, cnt_rev, cnt_fol, NU);

  // out_user = [mean_rev | mean_fol | x_user] @ Wt_user + b_user   (K=384)
  Srcs su{agg_rev, cnt_rev, agg_fol, cnt_fol, x_user, nullptr};
  gemm_kernel<<<(NU + 63) / 64, 256, 0, stream>>>(su, 3, Wt_user, b_user,
                                                  (float*)d_out, NU);
  // out_item = [mean_rates | x_item] @ Wt_item + b_item            (K=256)
  Srcs si{agg_rates, cnt_rates, x_item, nullptr, nullptr, nullptr};
  gemm_kernel<<<(NI + 63) / 64, 256, 0, stream>>>(si, 2, Wt_item, b_item,
                                                  (float*)d_out + (size_t)NU * D, NI);
}

// Round 2
// 995.387 us; speedup vs baseline: 1.3796x; 1.3796x over previous
//
#include <hip/hip_runtime.h>

#define D 128

// ---------------- phase 1: histogram of dst ----------------
__global__ void hist_kernel(const int* __restrict__ ei, int nedge,
                            int* __restrict__ cnt) {
  int i = blockIdx.x * 256 + threadIdx.x;
  if (i < nedge) atomicAdd(&cnt[ei[nedge + i]], 1);
}

// ---------------- phase 2: exclusive scan (one block per relation) --------
__global__ void scan_kernel(const int* c0, int* r0, int* u0, int n0,
                            const int* c1, int* r1, int* u1, int n1,
                            const int* c2, int* r2, int* u2, int n2) {
  const int* c; int* r; int* u; int n;
  if (blockIdx.x == 0)      { c = c0; r = r0; u = u0; n = n0; }
  else if (blockIdx.x == 1) { c = c1; r = r1; u = u1; n = n1; }
  else                      { c = c2; r = r2; u = u2; n = n2; }
  __shared__ int buf[1024];
  __shared__ int carry_s;
  const int tid = threadIdx.x;
  if (tid == 0) carry_s = 0;
  __syncthreads();
  for (int base = 0; base < n; base += 1024) {
    int v = (base + tid < n) ? c[base + tid] : 0;
    buf[tid] = v;
    __syncthreads();
    for (int off = 1; off < 1024; off <<= 1) {
      int t = (tid >= off) ? buf[tid - off] : 0;
      __syncthreads();
      buf[tid] += t;
      __syncthreads();
    }
    int incl = buf[tid];
    int carry = carry_s;
    if (base + tid < n) {
      int e = carry + incl - v;
      r[base + tid] = e;
      u[base + tid] = e;
    }
    __syncthreads();
    if (tid == 1023) carry_s = carry + incl;
    __syncthreads();
  }
  if (tid == 0) r[n] = carry_s;
}

// ---------------- phase 3: fill dst-sorted src list ----------------
__global__ void fill_kernel(const int* __restrict__ ei, int nedge,
                            int* __restrict__ cursor, int* __restrict__ esrc) {
  int i = blockIdx.x * 256 + threadIdx.x;
  if (i < nedge) {
    int pos = atomicAdd(&cursor[ei[nedge + i]], 1);
    esrc[pos] = ei[i];
  }
}

// ---------------- phase 4: gather + mean, one wave per dst row ------------
__global__ void __launch_bounds__(256) gather_kernel(
    const float* __restrict__ x, const int* __restrict__ rowptr,
    const int* __restrict__ esrc, float* __restrict__ mean, int M) {
  int row = blockIdx.x * 4 + (threadIdx.x >> 6);
  int lane = threadIdx.x & 63;
  if (row >= M) return;
  int beg = rowptr[row], end = rowptr[row + 1];
  float a0 = 0.0f, a1 = 0.0f;
  for (int j = beg; j < end; j++) {
    int s = esrc[j];
    const float* xr = x + (size_t)s * D;
    a0 += xr[lane];
    a1 += xr[lane + 64];
  }
  float inv = 1.0f / (float)max(end - beg, 1);
  mean[(size_t)row * D + lane] = a0 * inv;
  mean[(size_t)row * D + 64 + lane] = a1 * inv;
}

// ---------------- build combined transposed weights + biases ----------------
__global__ void prep_kernel(
    const float* __restrict__ Wl_rates, const float* __restrict__ Wr_rates, const float* __restrict__ bl_rates,
    const float* __restrict__ Wl_rev, const float* __restrict__ Wr_rev, const float* __restrict__ bl_rev,
    const float* __restrict__ Wl_fol, const float* __restrict__ Wr_fol, const float* __restrict__ bl_fol,
    float* __restrict__ Wt_item, float* __restrict__ Wt_user,
    float* __restrict__ b_item, float* __restrict__ b_user) {
  int idx = blockIdx.x * 256 + threadIdx.x;
  if (idx >= 384 * 128) return;
  int n = idx & 127;
  int k = idx >> 7;
  if (k < 256) {
    float v = (k < 128) ? Wl_rates[n * 128 + k] : Wr_rates[n * 128 + (k - 128)];
    Wt_item[k * 128 + n] = v;
  }
  float v;
  if (k < 128)      v = 0.5f * Wl_rev[n * 128 + k];
  else if (k < 256) v = 0.5f * Wl_fol[n * 128 + (k - 128)];
  else              v = 0.5f * (Wr_rev[n * 128 + (k - 256)] + Wr_fol[n * 128 + (k - 256)]);
  Wt_user[k * 128 + n] = v;
  if (idx < 128) {
    b_item[idx] = bl_rates[idx];
    b_user[idx] = 0.5f * (bl_rev[idx] + bl_fol[idx]);
  }
}

// ---------------- fp32 GEMM: out[M x 128] = A[M x K] * Wt[K x 128] + bias ----
struct Srcs { const float* s0; const float* s1; const float* s2; };

__global__ void __launch_bounds__(256) gemm_kernel(
    Srcs S, int nbuf, const float* __restrict__ Wt, const float* __restrict__ bias,
    float* __restrict__ out, int M) {
  __shared__ float Asub[64 * 64];    // 16 KB  [row][k]
  __shared__ float Wsub[64 * 128];   // 32 KB  [k][n]
  const int tid = threadIdx.x;
  const int tx = tid & 31;           // col group: cols tx*4 .. tx*4+3
  const int ty = tid >> 5;           // row group: rows ty*8 .. ty*8+7
  const int m0 = blockIdx.x * 64;

  float acc[8][4];
#pragma unroll
  for (int i = 0; i < 8; i++)
#pragma unroll
    for (int j = 0; j < 4; j++) acc[i][j] = 0.0f;

  const float* sbuf[3] = {S.s0, S.s1, S.s2};
  const int nchunks = nbuf * 2;      // 64-wide K chunks

  for (int c = 0; c < nchunks; c++) {
    const int kk0 = c * 64;
    const float* sp = sbuf[c >> 1];
    const int coff = (c & 1) * 64;
#pragma unroll
    for (int t = 0; t < 16; t++) {
      int lin = t * 256 + tid;       // row*64 + kk
      int row = lin >> 6, kk = lin & 63;
      int m = m0 + row;
      Asub[lin] = (m < M) ? sp[(size_t)m * D + coff + kk] : 0.0f;
    }
#pragma unroll
    for (int t = 0; t < 32; t++) {
      int lin = t * 256 + tid;       // kk*128 + n
      Wsub[lin] = Wt[(size_t)kk0 * 128 + lin];
    }
    __syncthreads();
#pragma unroll
    for (int k4 = 0; k4 < 16; k4++) {
      const int k = k4 * 4;
      float4 w0 = *(const float4*)&Wsub[(k + 0) * 128 + tx * 4];
      float4 w1 = *(const float4*)&Wsub[(k + 1) * 128 + tx * 4];
      float4 w2 = *(const float4*)&Wsub[(k + 2) * 128 + tx * 4];
      float4 w3 = *(const float4*)&Wsub[(k + 3) * 128 + tx * 4];
#pragma unroll
      for (int i = 0; i < 8; i++) {
        float4 a = *(const float4*)&Asub[(ty * 8 + i) * 64 + k];
        acc[i][0] += a.x * w0.x + a.y * w1.x + a.z * w2.x + a.w * w3.x;
        acc[i][1] += a.x * w0.y + a.y * w1.y + a.z * w2.y + a.w * w3.y;
        acc[i][2] += a.x * w0.z + a.y * w1.z + a.z * w2.z + a.w * w3.z;
        acc[i][3] += a.x * w0.w + a.y * w1.w + a.z * w2.w + a.w * w3.w;
      }
    }
    __syncthreads();
  }

  float4 bv = *(const float4*)&bias[tx * 4];
#pragma unroll
  for (int i = 0; i < 8; i++) {
    int m = m0 + ty * 8 + i;
    if (m < M) {
      float4 o;
      o.x = acc[i][0] + bv.x;
      o.y = acc[i][1] + bv.y;
      o.z = acc[i][2] + bv.z;
      o.w = acc[i][3] + bv.w;
      *(float4*)&out[(size_t)m * D + tx * 4] = o;
    }
  }
}

extern "C" void kernel_launch(void* const* d_in, const int* in_sizes, int n_in,
                              void* d_out, int out_size, void* d_ws, size_t ws_size,
                              hipStream_t stream) {
  const float* x_user   = (const float*)d_in[0];
  const float* x_item   = (const float*)d_in[1];
  const int*   ei_rates = (const int*)d_in[2];
  const int*   ei_rev   = (const int*)d_in[3];
  const int*   ei_fol   = (const int*)d_in[4];
  const float* Wl_rates = (const float*)d_in[5];
  const float* bl_rates = (const float*)d_in[6];
  const float* Wr_rates = (const float*)d_in[7];
  const float* Wl_rev   = (const float*)d_in[8];
  const float* bl_rev   = (const float*)d_in[9];
  const float* Wr_rev   = (const float*)d_in[10];
  const float* Wl_fol   = (const float*)d_in[11];
  const float* bl_fol   = (const float*)d_in[12];
  const float* Wr_fol   = (const float*)d_in[13];

  const int NU = in_sizes[0] / D;       // 50000
  const int NI = in_sizes[1] / D;       // 50000
  const int E_rates = in_sizes[2] / 2;  // 600000
  const int E_rev   = in_sizes[3] / 2;
  const int E_fol   = in_sizes[4] / 2;

  // ---- workspace carve-up (all offsets padded to 4-element multiples) ----
  int* wsi = (int*)d_ws;
  size_t off = 0;
  auto pad4 = [](size_t v) { return (v + 3) & ~(size_t)3; };
  int* cnt_rates = wsi + off; off += pad4(NI);
  int* cnt_rev   = wsi + off; off += pad4(NU);
  int* cnt_fol   = wsi + off; off += pad4(NU);
  const size_t cnt_floats = off;         // region to zero
  int* rp_rates  = wsi + off; off += pad4(NI + 1);
  int* rp_rev    = wsi + off; off += pad4(NU + 1);
  int* rp_fol    = wsi + off; off += pad4(NU + 1);
  int* cur_rates = wsi + off; off += pad4(NI);
  int* cur_rev   = wsi + off; off += pad4(NU);
  int* cur_fol   = wsi + off; off += pad4(NU);
  int* es_rates  = wsi + off; off += pad4(E_rates);
  int* es_rev    = wsi + off; off += pad4(E_rev);
  int* es_fol    = wsi + off; off += pad4(E_fol);
  float* wsf = (float*)d_ws;
  float* mean_rates = wsf + off; off += (size_t)NI * D;
  float* mean_rev   = wsf + off; off += (size_t)NU * D;
  float* mean_fol   = wsf + off; off += (size_t)NU * D;
  float* Wt_item    = wsf + off; off += 256 * 128;
  float* Wt_user    = wsf + off; off += 384 * 128;
  float* b_item     = wsf + off; off += 128;
  float* b_user     = wsf + off; off += 128;

  hipMemsetAsync(d_ws, 0, cnt_floats * sizeof(int), stream);
  prep_kernel<<<192, 256, 0, stream>>>(Wl_rates, Wr_rates, bl_rates,
                                       Wl_rev, Wr_rev, bl_rev,
                                       Wl_fol, Wr_fol, bl_fol,
                                       Wt_item, Wt_user, b_item, b_user);

  auto eb = [](int e) { return (e + 255) / 256; };
  hist_kernel<<<eb(E_rates), 256, 0, stream>>>(ei_rates, E_rates, cnt_rates);
  hist_kernel<<<eb(E_rev),   256, 0, stream>>>(ei_rev,   E_rev,   cnt_rev);
  hist_kernel<<<eb(E_fol),   256, 0, stream>>>(ei_fol,   E_fol,   cnt_fol);

  scan_kernel<<<3, 1024, 0, stream>>>(cnt_rates, rp_rates, cur_rates, NI,
                                      cnt_rev,   rp_rev,   cur_rev,   NU,
                                      cnt_fol,   rp_fol,   cur_fol,   NU);

  fill_kernel<<<eb(E_rates), 256, 0, stream>>>(ei_rates, E_rates, cur_rates, es_rates);
  fill_kernel<<<eb(E_rev),   256, 0, stream>>>(ei_rev,   E_rev,   cur_rev,   es_rev);
  fill_kernel<<<eb(E_fol),   256, 0, stream>>>(ei_fol,   E_fol,   cur_fol,   es_fol);

  gather_kernel<<<(NI + 3) / 4, 256, 0, stream>>>(x_user, rp_rates, es_rates, mean_rates, NI);
  gather_kernel<<<(NU + 3) / 4, 256, 0, stream>>>(x_item, rp_rev,   es_rev,   mean_rev,   NU);
  gather_kernel<<<(NU + 3) / 4, 256, 0, stream>>>(x_user, rp_fol,   es_fol,   mean_fol,   NU);

  // out_user = [mean_rev | mean_fol | x_user] @ Wt_user + b_user   (K=384)
  Srcs su{mean_rev, mean_fol, x_user};
  gemm_kernel<<<(NU + 63) / 64, 256, 0, stream>>>(su, 3, Wt_user, b_user,
                                                  (float*)d_out, NU);
  // out_item = [mean_rates | x_item] @ Wt_item + b_item            (K=256)
  Srcs si{mean_rates, x_item, nullptr};
  gemm_kernel<<<(NI + 63) / 64, 256, 0, stream>>>(si, 2, Wt_item, b_item,
                                                  (float*)d_out + (size_t)NU * D, NI);
}

// Round 3
// 649.216 us; speedup vs baseline: 2.1152x; 1.5332x over previous
//
#include <hip/hip_runtime.h>

#define D 128

typedef __attribute__((ext_vector_type(8))) short bf16x8;
typedef __attribute__((ext_vector_type(4))) float f32x4;

__device__ inline unsigned short f2bf(float f) {
  unsigned u = __builtin_bit_cast(unsigned, f);
  unsigned r = u + 0x7FFFu + ((u >> 16) & 1u);
  return (unsigned short)(r >> 16);
}
__device__ inline float bf2f(unsigned short b) {
  unsigned u = ((unsigned)b) << 16;
  return __builtin_bit_cast(float, u);
}

// ---------------- fp32 -> bf16 table conversion ----------------
__global__ void __launch_bounds__(256) conv_kernel(const float* __restrict__ x,
                                                   unsigned short* __restrict__ xb,
                                                   int n4) {
  int i = blockIdx.x * 256 + threadIdx.x;
  if (i >= n4) return;
  float4 v = ((const float4*)x)[i];
  ushort4 o;
  o.x = f2bf(v.x); o.y = f2bf(v.y); o.z = f2bf(v.z); o.w = f2bf(v.w);
  ((ushort4*)xb)[i] = o;
}

// ---------------- phase 1: histogram of dst ----------------
__global__ void hist_kernel(const int* __restrict__ ei, int nedge,
                            int* __restrict__ cnt) {
  int i = blockIdx.x * 256 + threadIdx.x;
  if (i < nedge) atomicAdd(&cnt[ei[nedge + i]], 1);
}

// ---------------- phase 2: scan, serial-per-thread + one block scan -------
struct ScanArgs { const int* c[3]; int* r[3]; int* u[3]; int n[3]; };

__global__ void __launch_bounds__(1024) scan_kernel(ScanArgs A) {
  int rel = blockIdx.x;
  const int* c = A.c[rel]; int* r = A.r[rel]; int* u = A.u[rel];
  const int n = A.n[rel];
  __shared__ int buf[1024];
  const int tid = threadIdx.x;
  const int chunk = (n + 1023) >> 10;
  const int base = tid * chunk;
  const int lim = min(base + chunk, n);
  int s = 0;
  for (int j = base; j < lim; j++) s += c[j];
  buf[tid] = s;
  __syncthreads();
  for (int off = 1; off < 1024; off <<= 1) {
    int t = (tid >= off) ? buf[tid - off] : 0;
    __syncthreads();
    buf[tid] += t;
    __syncthreads();
  }
  int run = buf[tid] - s;   // exclusive
  for (int j = base; j < lim; j++) {
    r[j] = run; u[j] = run;
    run += c[j];
  }
  if (tid == 1023) r[n] = buf[1023];
}

// ---------------- phase 3: fill dst-sorted src list ----------------
__global__ void fill_kernel(const int* __restrict__ ei, int nedge,
                            int* __restrict__ cursor, int* __restrict__ esrc) {
  int i = blockIdx.x * 256 + threadIdx.x;
  if (i < nedge) {
    int pos = atomicAdd(&cursor[ei[nedge + i]], 1);
    esrc[pos] = ei[i];
  }
}

// ---------------- phase 4: gather + mean (bf16 in/out, fp32 accum) --------
__global__ void __launch_bounds__(256) gather_kernel(
    const unsigned short* __restrict__ xb, const int* __restrict__ rowptr,
    const int* __restrict__ esrc, unsigned short* __restrict__ mean, int M) {
  int row = blockIdx.x * 4 + (threadIdx.x >> 6);
  int lane = threadIdx.x & 63;
  if (row >= M) return;
  int beg = rowptr[row], end = rowptr[row + 1];
  float a0 = 0.0f, a1 = 0.0f;
  for (int j = beg; j < end; j++) {
    int s = esrc[j];
    unsigned v = *(const unsigned*)(xb + (size_t)s * D + lane * 2);
    a0 += bf2f((unsigned short)(v & 0xFFFFu));
    a1 += bf2f((unsigned short)(v >> 16));
  }
  float inv = 1.0f / (float)max(end - beg, 1);
  unsigned o = (unsigned)f2bf(a0 * inv) | ((unsigned)f2bf(a1 * inv) << 16);
  *(unsigned*)(mean + (size_t)row * D + lane * 2) = o;
}

// ---------------- prep: combined bf16 weights (n-major) + biases ----------
// Wb_user[128][384]: [0.5*Wl_rev | 0.5*Wl_fol | 0.5*(Wr_rev+Wr_fol)] per row n
// Wb_item[128][256]: [Wl_rates | Wr_rates] per row n
__global__ void __launch_bounds__(384) prep_kernel(
    const float* __restrict__ Wl_rates, const float* __restrict__ Wr_rates, const float* __restrict__ bl_rates,
    const float* __restrict__ Wl_rev, const float* __restrict__ Wr_rev, const float* __restrict__ bl_rev,
    const float* __restrict__ Wl_fol, const float* __restrict__ Wr_fol, const float* __restrict__ bl_fol,
    unsigned short* __restrict__ Wb_user, unsigned short* __restrict__ Wb_item,
    float* __restrict__ b_user, float* __restrict__ b_item) {
  int n = blockIdx.x;          // 0..127
  int k = threadIdx.x;         // 0..383
  float v;
  if (k < 128)      v = 0.5f * Wl_rev[n * 128 + k];
  else if (k < 256) v = 0.5f * Wl_fol[n * 128 + (k - 128)];
  else              v = 0.5f * (Wr_rev[n * 128 + (k - 256)] + Wr_fol[n * 128 + (k - 256)]);
  Wb_user[n * 384 + k] = f2bf(v);
  if (k < 256) {
    float w = (k < 128) ? Wl_rates[n * 128 + k] : Wr_rates[n * 128 + (k - 128)];
    Wb_item[n * 256 + k] = f2bf(w);
  }
  if (n == 0 && k < 128) {
    b_item[k] = bl_rates[k];
    b_user[k] = 0.5f * (bl_rev[k] + bl_fol[k]);
  }
}

// ---------------- bf16 MFMA GEMM: out[M x 128] = A[M x K] * W^T + bias ----
// A = virtual concat of nbuf [M][128] bf16 buffers; Wb is [128][K] bf16
// (n-major). Block: 256 thr = 4 waves (2x2), tile 64 rows x 128 cols.
struct BSrcs { const unsigned short* s[3]; };

__global__ void __launch_bounds__(256) gemm_kernel(
    BSrcs S, const unsigned short* __restrict__ Wb, int K,
    const float* __restrict__ bias, float* __restrict__ out, int M) {
  __shared__ __align__(16) unsigned short As[64][72];
  __shared__ __align__(16) unsigned short Ws[128][72];
  const int tid = threadIdx.x;
  const int lane = tid & 63;
  const int wave = tid >> 6;
  const int wrow = (wave >> 1) * 32;
  const int wcol = (wave & 1) * 64;
  const int l15 = lane & 15;
  const int quad = lane >> 4;
  const int m0 = blockIdx.x * 64;

  f32x4 acc[2][4];
#pragma unroll
  for (int r = 0; r < 2; r++)
#pragma unroll
    for (int c = 0; c < 4; c++) acc[r][c] = (f32x4){0.f, 0.f, 0.f, 0.f};

  const int nchunks = K >> 6;
  for (int ch = 0; ch < nchunks; ch++) {
    const unsigned short* sp = S.s[ch >> 1];
    const int coff = (ch & 1) << 6;
    // stage A: 64 rows x 64 k (bf16). thread: row=tid>>2, part=tid&3
    {
      int row = tid >> 2, part = tid & 3;
      int m = m0 + row;
      uint4 v0 = {0, 0, 0, 0}, v1 = {0, 0, 0, 0};
      if (m < M) {
        const uint4* g = (const uint4*)(sp + (size_t)m * D + coff + part * 16);
        v0 = g[0]; v1 = g[1];
      }
      uint4* l = (uint4*)(&As[row][part * 16]);
      l[0] = v0; l[1] = v1;
    }
    // stage W: 128 n x 64 k. thread: n=tid>>1, half=tid&1
    {
      int n = tid >> 1, half = tid & 1;
      const uint4* g = (const uint4*)(Wb + (size_t)n * K + ch * 64 + half * 32);
      uint4* l = (uint4*)(&Ws[n][half * 32]);
      l[0] = g[0]; l[1] = g[1]; l[2] = g[2]; l[3] = g[3];
    }
    __syncthreads();
#pragma unroll
    for (int kk = 0; kk < 64; kk += 32) {
      const int kb = kk + quad * 8;
      bf16x8 a0 = *(const bf16x8*)&As[wrow + l15][kb];
      bf16x8 a1 = *(const bf16x8*)&As[wrow + 16 + l15][kb];
      bf16x8 b0 = *(const bf16x8*)&Ws[wcol + l15][kb];
      bf16x8 b1 = *(const bf16x8*)&Ws[wcol + 16 + l15][kb];
      bf16x8 b2 = *(const bf16x8*)&Ws[wcol + 32 + l15][kb];
      bf16x8 b3 = *(const bf16x8*)&Ws[wcol + 48 + l15][kb];
      acc[0][0] = __builtin_amdgcn_mfma_f32_16x16x32_bf16(a0, b0, acc[0][0], 0, 0, 0);
      acc[0][1] = __builtin_amdgcn_mfma_f32_16x16x32_bf16(a0, b1, acc[0][1], 0, 0, 0);
      acc[0][2] = __builtin_amdgcn_mfma_f32_16x16x32_bf16(a0, b2, acc[0][2], 0, 0, 0);
      acc[0][3] = __builtin_amdgcn_mfma_f32_16x16x32_bf16(a0, b3, acc[0][3], 0, 0, 0);
      acc[1][0] = __builtin_amdgcn_mfma_f32_16x16x32_bf16(a1, b0, acc[1][0], 0, 0, 0);
      acc[1][1] = __builtin_amdgcn_mfma_f32_16x16x32_bf16(a1, b1, acc[1][1], 0, 0, 0);
      acc[1][2] = __builtin_amdgcn_mfma_f32_16x16x32_bf16(a1, b2, acc[1][2], 0, 0, 0);
      acc[1][3] = __builtin_amdgcn_mfma_f32_16x16x32_bf16(a1, b3, acc[1][3], 0, 0, 0);
    }
    __syncthreads();
  }
  // epilogue: C/D layout col=lane&15, row=quad*4+reg
#pragma unroll
  for (int c = 0; c < 4; c++) {
    const int n = wcol + c * 16 + l15;
    const float bv = bias[n];
#pragma unroll
    for (int r = 0; r < 2; r++) {
      const int mrow = m0 + wrow + r * 16 + quad * 4;
#pragma unroll
      for (int i = 0; i < 4; i++) {
        if (mrow + i < M) out[(size_t)(mrow + i) * D + n] = acc[r][c][i] + bv;
      }
    }
  }
}

extern "C" void kernel_launch(void* const* d_in, const int* in_sizes, int n_in,
                              void* d_out, int out_size, void* d_ws, size_t ws_size,
                              hipStream_t stream) {
  const float* x_user   = (const float*)d_in[0];
  const float* x_item   = (const float*)d_in[1];
  const int*   ei_rates = (const int*)d_in[2];
  const int*   ei_rev   = (const int*)d_in[3];
  const int*   ei_fol   = (const int*)d_in[4];
  const float* Wl_rates = (const float*)d_in[5];
  const float* bl_rates = (const float*)d_in[6];
  const float* Wr_rates = (const float*)d_in[7];
  const float* Wl_rev   = (const float*)d_in[8];
  const float* bl_rev   = (const float*)d_in[9];
  const float* Wr_rev   = (const float*)d_in[10];
  const float* Wl_fol   = (const float*)d_in[11];
  const float* bl_fol   = (const float*)d_in[12];
  const float* Wr_fol   = (const float*)d_in[13];

  const int NU = in_sizes[0] / D;       // 50000
  const int NI = in_sizes[1] / D;       // 50000
  const int E_rates = in_sizes[2] / 2;
  const int E_rev   = in_sizes[3] / 2;
  const int E_fol   = in_sizes[4] / 2;

  // ---- workspace carve-up (byte-based, 16B aligned) ----
  char* wsb = (char*)d_ws;
  size_t off = 0;
  auto take = [&](size_t bytes) {
    char* p = wsb + off;
    off += (bytes + 15) & ~(size_t)15;
    return p;
  };
  int* cnt_rates = (int*)take((size_t)NI * 4);
  int* cnt_rev   = (int*)take((size_t)NU * 4);
  int* cnt_fol   = (int*)take((size_t)NU * 4);
  const size_t cnt_bytes = off;          // region to zero
  int* rp_rates  = (int*)take((size_t)(NI + 1) * 4);
  int* rp_rev    = (int*)take((size_t)(NU + 1) * 4);
  int* rp_fol    = (int*)take((size_t)(NU + 1) * 4);
  int* cur_rates = (int*)take((size_t)NI * 4);
  int* cur_rev   = (int*)take((size_t)NU * 4);
  int* cur_fol   = (int*)take((size_t)NU * 4);
  int* es_rates  = (int*)take((size_t)E_rates * 4);
  int* es_rev    = (int*)take((size_t)E_rev * 4);
  int* es_fol    = (int*)take((size_t)E_fol * 4);
  unsigned short* xb_user    = (unsigned short*)take((size_t)NU * D * 2);
  unsigned short* xb_item    = (unsigned short*)take((size_t)NI * D * 2);
  unsigned short* mean_rates = (unsigned short*)take((size_t)NI * D * 2);
  unsigned short* mean_rev   = (unsigned short*)take((size_t)NU * D * 2);
  unsigned short* mean_fol   = (unsigned short*)take((size_t)NU * D * 2);
  unsigned short* Wb_user    = (unsigned short*)take(128 * 384 * 2);
  unsigned short* Wb_item    = (unsigned short*)take(128 * 256 * 2);
  float* b_user = (float*)take(128 * 4);
  float* b_item = (float*)take(128 * 4);

  hipMemsetAsync(d_ws, 0, cnt_bytes, stream);
  prep_kernel<<<128, 384, 0, stream>>>(Wl_rates, Wr_rates, bl_rates,
                                       Wl_rev, Wr_rev, bl_rev,
                                       Wl_fol, Wr_fol, bl_fol,
                                       Wb_user, Wb_item, b_user, b_item);
  conv_kernel<<<(NU * D / 4 + 255) / 256, 256, 0, stream>>>(x_user, xb_user, NU * D / 4);
  conv_kernel<<<(NI * D / 4 + 255) / 256, 256, 0, stream>>>(x_item, xb_item, NI * D / 4);

  auto eb = [](int e) { return (e + 255) / 256; };
  hist_kernel<<<eb(E_rates), 256, 0, stream>>>(ei_rates, E_rates, cnt_rates);
  hist_kernel<<<eb(E_rev),   256, 0, stream>>>(ei_rev,   E_rev,   cnt_rev);
  hist_kernel<<<eb(E_fol),   256, 0, stream>>>(ei_fol,   E_fol,   cnt_fol);

  ScanArgs sa;
  sa.c[0] = cnt_rates; sa.r[0] = rp_rates; sa.u[0] = cur_rates; sa.n[0] = NI;
  sa.c[1] = cnt_rev;   sa.r[1] = rp_rev;   sa.u[1] = cur_rev;   sa.n[1] = NU;
  sa.c[2] = cnt_fol;   sa.r[2] = rp_fol;   sa.u[2] = cur_fol;   sa.n[2] = NU;
  scan_kernel<<<3, 1024, 0, stream>>>(sa);

  fill_kernel<<<eb(E_rates), 256, 0, stream>>>(ei_rates, E_rates, cur_rates, es_rates);
  fill_kernel<<<eb(E_rev),   256, 0, stream>>>(ei_rev,   E_rev,   cur_rev,   es_rev);
  fill_kernel<<<eb(E_fol),   256, 0, stream>>>(ei_fol,   E_fol,   cur_fol,   es_fol);

  gather_kernel<<<(NI + 3) / 4, 256, 0, stream>>>(xb_user, rp_rates, es_rates, mean_rates, NI);
  gather_kernel<<<(NU + 3) / 4, 256, 0, stream>>>(xb_item, rp_rev,   es_rev,   mean_rev,   NU);
  gather_kernel<<<(NU + 3) / 4, 256, 0, stream>>>(xb_user, rp_fol,   es_fol,   mean_fol,   NU);

  // out_user = [mean_rev | mean_fol | xb_user] @ Wb_user^T + b_user  (K=384)
  BSrcs su; su.s[0] = mean_rev; su.s[1] = mean_fol; su.s[2] = xb_user;
  gemm_kernel<<<(NU + 63) / 64, 256, 0, stream>>>(su, Wb_user, 384, b_user,
                                                  (float*)d_out, NU);
  // out_item = [mean_rates | xb_item] @ Wb_item^T + b_item           (K=256)
  BSrcs si; si.s[0] = mean_rates; si.s[1] = xb_item; si.s[2] = nullptr;
  gemm_kernel<<<(NI + 63) / 64, 256, 0, stream>>>(si, Wb_item, 256, b_item,
                                                  (float*)d_out + (size_t)NU * D, NI);
}

// Round 4
// 554.287 us; speedup vs baseline: 2.4775x; 1.1713x over previous
//
#include <hip/hip_runtime.h>

#define D 128
#define SCHUNK 4096

typedef __attribute__((ext_vector_type(8))) short bf16x8;
typedef __attribute__((ext_vector_type(4))) float f32x4;

__device__ inline unsigned short f2bf(float f) {
  unsigned u = __builtin_bit_cast(unsigned, f);
  unsigned r = u + 0x7FFFu + ((u >> 16) & 1u);
  return (unsigned short)(r >> 16);
}
__device__ inline float bf2f(unsigned short b) {
  unsigned u = ((unsigned)b) << 16;
  return __builtin_bit_cast(float, u);
}

// ---------------- fp32 -> bf16 table conversion ----------------
__global__ void __launch_bounds__(256) conv_kernel(const float* __restrict__ x,
                                                   unsigned short* __restrict__ xb,
                                                   int n4) {
  int i = blockIdx.x * 256 + threadIdx.x;
  if (i >= n4) return;
  float4 v = ((const float4*)x)[i];
  ushort4 o;
  o.x = f2bf(v.x); o.y = f2bf(v.y); o.z = f2bf(v.z); o.w = f2bf(v.w);
  ((ushort4*)xb)[i] = o;
}

// ---------------- phase 1: histogram of dst ----------------
__global__ void hist_kernel(const int* __restrict__ ei, int nedge,
                            int* __restrict__ cnt) {
  int i = blockIdx.x * 256 + threadIdx.x;
  if (i < nedge) atomicAdd(&cnt[ei[nedge + i]], 1);
}

// ---------------- hierarchical exclusive scan over 3 relations ----------
struct ScanP { const int* c; int* r; int* u; int n; int nb; };

__device__ inline ScanP pick_rel(int& b, ScanP p0, ScanP p1, ScanP p2) {
  if (b < p0.nb) return p0;
  b -= p0.nb;
  if (b < p1.nb) return p1;
  b -= p1.nb;
  return p2;
}

// pass 1: per-block (4096 elem) sums
__global__ void __launch_bounds__(256) scan1_kernel(ScanP p0, ScanP p1, ScanP p2,
                                                    int* __restrict__ bsum) {
  int b = blockIdx.x;
  ScanP p = pick_rel(b, p0, p1, p2);
  const int tid = threadIdx.x;
  const int base = b * SCHUNK + tid * 16;
  int s = 0;
#pragma unroll
  for (int v = 0; v < 4; v++) {
    int idx = base + v * 4;
    if (idx + 3 < p.n) {
      int4 t = *(const int4*)(p.c + idx);
      s += t.x + t.y + t.z + t.w;
    } else {
#pragma unroll
      for (int e = 0; e < 4; e++)
        if (idx + e < p.n) s += p.c[idx + e];
    }
  }
  __shared__ int red[256];
  red[tid] = s;
  __syncthreads();
  for (int off = 128; off > 0; off >>= 1) {
    if (tid < off) red[tid] += red[tid + off];
    __syncthreads();
  }
  if (tid == 0) bsum[blockIdx.x] = red[0];
}

// pass 2: exclusive-scan the block sums per relation (<=16 each); write totals
__global__ void scan2_kernel(ScanP p0, ScanP p1, ScanP p2, int* __restrict__ bsum) {
  int t = threadIdx.x;
  if (t >= 3) return;
  ScanP p = (t == 0) ? p0 : (t == 1) ? p1 : p2;
  int boff = (t == 0) ? 0 : (t == 1) ? p0.nb : p0.nb + p1.nb;
  int run = 0;
  for (int i = 0; i < p.nb; i++) {
    int v = bsum[boff + i];
    bsum[boff + i] = run;
    run += v;
  }
  p.r[p.n] = run;
}

// pass 3: local scan + global offset -> rowptr + cursor
__global__ void __launch_bounds__(256) scan3_kernel(ScanP p0, ScanP p1, ScanP p2,
                                                    const int* __restrict__ bsum) {
  int b = blockIdx.x;
  ScanP p = pick_rel(b, p0, p1, p2);
  const int tid = threadIdx.x;
  const int base = b * SCHUNK + tid * 16;
  int vals[16];
  int s = 0;
#pragma unroll
  for (int v = 0; v < 4; v++) {
    int idx = base + v * 4;
    int4 t = {0, 0, 0, 0};
    if (idx + 3 < p.n) {
      t = *(const int4*)(p.c + idx);
    } else {
      if (idx + 0 < p.n) t.x = p.c[idx + 0];
      if (idx + 1 < p.n) t.y = p.c[idx + 1];
      if (idx + 2 < p.n) t.z = p.c[idx + 2];
      if (idx + 3 < p.n) t.w = p.c[idx + 3];
    }
    vals[v * 4 + 0] = t.x; vals[v * 4 + 1] = t.y;
    vals[v * 4 + 2] = t.z; vals[v * 4 + 3] = t.w;
    s += t.x + t.y + t.z + t.w;
  }
  __shared__ int buf[256];
  buf[tid] = s;
  __syncthreads();
  for (int off = 1; off < 256; off <<= 1) {
    int t = (tid >= off) ? buf[tid - off] : 0;
    __syncthreads();
    buf[tid] += t;
    __syncthreads();
  }
  int run = buf[tid] - s + bsum[blockIdx.x];  // exclusive + block offset
#pragma unroll
  for (int v = 0; v < 16; v++) {
    int idx = base + v;
    if (idx < p.n) { p.r[idx] = run; p.u[idx] = run; }
    run += vals[v];
  }
}

// ---------------- phase 3: fill dst-sorted src list ----------------
__global__ void fill_kernel(const int* __restrict__ ei, int nedge,
                            int* __restrict__ cursor, int* __restrict__ esrc) {
  int i = blockIdx.x * 256 + threadIdx.x;
  if (i < nedge) {
    int pos = atomicAdd(&cursor[ei[nedge + i]], 1);
    esrc[pos] = ei[i];
  }
}

// ---------------- phase 4: gather + mean (bf16 in/out, fp32 accum) --------
__global__ void __launch_bounds__(256) gather_kernel(
    const unsigned short* __restrict__ xb, const int* __restrict__ rowptr,
    const int* __restrict__ esrc, unsigned short* __restrict__ mean, int M) {
  int row = blockIdx.x * 4 + (threadIdx.x >> 6);
  int lane = threadIdx.x & 63;
  if (row >= M) return;
  int beg = rowptr[row], end = rowptr[row + 1];
  float a0 = 0.0f, a1 = 0.0f;
  for (int j = beg; j < end; j++) {
    int s = esrc[j];
    unsigned v = *(const unsigned*)(xb + (size_t)s * D + lane * 2);
    a0 += bf2f((unsigned short)(v & 0xFFFFu));
    a1 += bf2f((unsigned short)(v >> 16));
  }
  float inv = 1.0f / (float)max(end - beg, 1);
  unsigned o = (unsigned)f2bf(a0 * inv) | ((unsigned)f2bf(a1 * inv) << 16);
  *(unsigned*)(mean + (size_t)row * D + lane * 2) = o;
}

// ---------------- prep: combined bf16 weights (n-major) + biases ----------
__global__ void __launch_bounds__(384) prep_kernel(
    const float* __restrict__ Wl_rates, const float* __restrict__ Wr_rates, const float* __restrict__ bl_rates,
    const float* __restrict__ Wl_rev, const float* __restrict__ Wr_rev, const float* __restrict__ bl_rev,
    const float* __restrict__ Wl_fol, const float* __restrict__ Wr_fol, const float* __restrict__ bl_fol,
    unsigned short* __restrict__ Wb_user, unsigned short* __restrict__ Wb_item,
    float* __restrict__ b_user, float* __restrict__ b_item) {
  int n = blockIdx.x;          // 0..127
  int k = threadIdx.x;         // 0..383
  float v;
  if (k < 128)      v = 0.5f * Wl_rev[n * 128 + k];
  else if (k < 256) v = 0.5f * Wl_fol[n * 128 + (k - 128)];
  else              v = 0.5f * (Wr_rev[n * 128 + (k - 256)] + Wr_fol[n * 128 + (k - 256)]);
  Wb_user[n * 384 + k] = f2bf(v);
  if (k < 256) {
    float w = (k < 128) ? Wl_rates[n * 128 + k] : Wr_rates[n * 128 + (k - 128)];
    Wb_item[n * 256 + k] = f2bf(w);
  }
  if (n == 0 && k < 128) {
    b_item[k] = bl_rates[k];
    b_user[k] = 0.5f * (bl_rev[k] + bl_fol[k]);
  }
}

// ---------------- bf16 MFMA GEMM: out[M x 128] = A[M x K] * W^T + bias ----
struct BSrcs { const unsigned short* s[3]; };

__global__ void __launch_bounds__(256) gemm_kernel(
    BSrcs S, const unsigned short* __restrict__ Wb, int K,
    const float* __restrict__ bias, float* __restrict__ out, int M) {
  __shared__ __align__(16) unsigned short As[64][72];
  __shared__ __align__(16) unsigned short Ws[128][72];
  const int tid = threadIdx.x;
  const int lane = tid & 63;
  const int wave = tid >> 6;
  const int wrow = (wave >> 1) * 32;
  const int wcol = (wave & 1) * 64;
  const int l15 = lane & 15;
  const int quad = lane >> 4;
  const int m0 = blockIdx.x * 64;

  f32x4 acc[2][4];
#pragma unroll
  for (int r = 0; r < 2; r++)
#pragma unroll
    for (int c = 0; c < 4; c++) acc[r][c] = (f32x4){0.f, 0.f, 0.f, 0.f};

  const int nchunks = K >> 6;
  for (int ch = 0; ch < nchunks; ch++) {
    const unsigned short* sp = S.s[ch >> 1];
    const int coff = (ch & 1) << 6;
    {
      int row = tid >> 2, part = tid & 3;
      int m = m0 + row;
      uint4 v0 = {0, 0, 0, 0}, v1 = {0, 0, 0, 0};
      if (m < M) {
        const uint4* g = (const uint4*)(sp + (size_t)m * D + coff + part * 16);
        v0 = g[0]; v1 = g[1];
      }
      uint4* l = (uint4*)(&As[row][part * 16]);
      l[0] = v0; l[1] = v1;
    }
    {
      int n = tid >> 1, half = tid & 1;
      const uint4* g = (const uint4*)(Wb + (size_t)n * K + ch * 64 + half * 32);
      uint4* l = (uint4*)(&Ws[n][half * 32]);
      l[0] = g[0]; l[1] = g[1]; l[2] = g[2]; l[3] = g[3];
    }
    __syncthreads();
#pragma unroll
    for (int kk = 0; kk < 64; kk += 32) {
      const int kb = kk + quad * 8;
      bf16x8 a0 = *(const bf16x8*)&As[wrow + l15][kb];
      bf16x8 a1 = *(const bf16x8*)&As[wrow + 16 + l15][kb];
      bf16x8 b0 = *(const bf16x8*)&Ws[wcol + l15][kb];
      bf16x8 b1 = *(const bf16x8*)&Ws[wcol + 16 + l15][kb];
      bf16x8 b2 = *(const bf16x8*)&Ws[wcol + 32 + l15][kb];
      bf16x8 b3 = *(const bf16x8*)&Ws[wcol + 48 + l15][kb];
      acc[0][0] = __builtin_amdgcn_mfma_f32_16x16x32_bf16(a0, b0, acc[0][0], 0, 0, 0);
      acc[0][1] = __builtin_amdgcn_mfma_f32_16x16x32_bf16(a0, b1, acc[0][1], 0, 0, 0);
      acc[0][2] = __builtin_amdgcn_mfma_f32_16x16x32_bf16(a0, b2, acc[0][2], 0, 0, 0);
      acc[0][3] = __builtin_amdgcn_mfma_f32_16x16x32_bf16(a0, b3, acc[0][3], 0, 0, 0);
      acc[1][0] = __builtin_amdgcn_mfma_f32_16x16x32_bf16(a1, b0, acc[1][0], 0, 0, 0);
      acc[1][1] = __builtin_amdgcn_mfma_f32_16x16x32_bf16(a1, b1, acc[1][1], 0, 0, 0);
      acc[1][2] = __builtin_amdgcn_mfma_f32_16x16x32_bf16(a1, b2, acc[1][2], 0, 0, 0);
      acc[1][3] = __builtin_amdgcn_mfma_f32_16x16x32_bf16(a1, b3, acc[1][3], 0, 0, 0);
    }
    __syncthreads();
  }
#pragma unroll
  for (int c = 0; c < 4; c++) {
    const int n = wcol + c * 16 + l15;
    const float bv = bias[n];
#pragma unroll
    for (int r = 0; r < 2; r++) {
      const int mrow = m0 + wrow + r * 16 + quad * 4;
#pragma unroll
      for (int i = 0; i < 4; i++) {
        if (mrow + i < M) out[(size_t)(mrow + i) * D + n] = acc[r][c][i] + bv;
      }
    }
  }
}

extern "C" void kernel_launch(void* const* d_in, const int* in_sizes, int n_in,
                              void* d_out, int out_size, void* d_ws, size_t ws_size,
                              hipStream_t stream) {
  const float* x_user   = (const float*)d_in[0];
  const float* x_item   = (const float*)d_in[1];
  const int*   ei_rates = (const int*)d_in[2];
  const int*   ei_rev   = (const int*)d_in[3];
  const int*   ei_fol   = (const int*)d_in[4];
  const float* Wl_rates = (const float*)d_in[5];
  const float* bl_rates = (const float*)d_in[6];
  const float* Wr_rates = (const float*)d_in[7];
  const float* Wl_rev   = (const float*)d_in[8];
  const float* bl_rev   = (const float*)d_in[9];
  const float* Wr_rev   = (const float*)d_in[10];
  const float* Wl_fol   = (const float*)d_in[11];
  const float* bl_fol   = (const float*)d_in[12];
  const float* Wr_fol   = (const float*)d_in[13];

  const int NU = in_sizes[0] / D;       // 50000
  const int NI = in_sizes[1] / D;       // 50000
  const int E_rates = in_sizes[2] / 2;
  const int E_rev   = in_sizes[3] / 2;
  const int E_fol   = in_sizes[4] / 2;

  // ---- workspace carve-up (byte-based, 16B aligned) ----
  char* wsb = (char*)d_ws;
  size_t off = 0;
  auto take = [&](size_t bytes) {
    char* p = wsb + off;
    off += (bytes + 15) & ~(size_t)15;
    return p;
  };
  int* cnt_rates = (int*)take((size_t)NI * 4);
  int* cnt_rev   = (int*)take((size_t)NU * 4);
  int* cnt_fol   = (int*)take((size_t)NU * 4);
  const size_t cnt_bytes = off;          // region to zero
  int* rp_rates  = (int*)take((size_t)(NI + 1) * 4);
  int* rp_rev    = (int*)take((size_t)(NU + 1) * 4);
  int* rp_fol    = (int*)take((size_t)(NU + 1) * 4);
  int* cur_rates = (int*)take((size_t)NI * 4);
  int* cur_rev   = (int*)take((size_t)NU * 4);
  int* cur_fol   = (int*)take((size_t)NU * 4);
  int* es_rates  = (int*)take((size_t)E_rates * 4);
  int* es_rev    = (int*)take((size_t)E_rev * 4);
  int* es_fol    = (int*)take((size_t)E_fol * 4);
  int* bsum      = (int*)take(256 * 4);
  unsigned short* xb_user    = (unsigned short*)take((size_t)NU * D * 2);
  unsigned short* xb_item    = (unsigned short*)take((size_t)NI * D * 2);
  unsigned short* mean_rates = (unsigned short*)take((size_t)NI * D * 2);
  unsigned short* mean_rev   = (unsigned short*)take((size_t)NU * D * 2);
  unsigned short* mean_fol   = (unsigned short*)take((size_t)NU * D * 2);
  unsigned short* Wb_user    = (unsigned short*)take(128 * 384 * 2);
  unsigned short* Wb_item    = (unsigned short*)take(128 * 256 * 2);
  float* b_user = (float*)take(128 * 4);
  float* b_item = (float*)take(128 * 4);

  hipMemsetAsync(d_ws, 0, cnt_bytes, stream);
  prep_kernel<<<128, 384, 0, stream>>>(Wl_rates, Wr_rates, bl_rates,
                                       Wl_rev, Wr_rev, bl_rev,
                                       Wl_fol, Wr_fol, bl_fol,
                                       Wb_user, Wb_item, b_user, b_item);
  conv_kernel<<<(NU * D / 4 + 255) / 256, 256, 0, stream>>>(x_user, xb_user, NU * D / 4);
  conv_kernel<<<(NI * D / 4 + 255) / 256, 256, 0, stream>>>(x_item, xb_item, NI * D / 4);

  auto eb = [](int e) { return (e + 255) / 256; };
  hist_kernel<<<eb(E_rates), 256, 0, stream>>>(ei_rates, E_rates, cnt_rates);
  hist_kernel<<<eb(E_rev),   256, 0, stream>>>(ei_rev,   E_rev,   cnt_rev);
  hist_kernel<<<eb(E_fol),   256, 0, stream>>>(ei_fol,   E_fol,   cnt_fol);

  auto nb = [](int n) { return (n + SCHUNK - 1) / SCHUNK; };
  ScanP p0{cnt_rates, rp_rates, cur_rates, NI, nb(NI)};
  ScanP p1{cnt_rev,   rp_rev,   cur_rev,   NU, nb(NU)};
  ScanP p2{cnt_fol,   rp_fol,   cur_fol,   NU, nb(NU)};
  const int nbtot = p0.nb + p1.nb + p2.nb;
  scan1_kernel<<<nbtot, 256, 0, stream>>>(p0, p1, p2, bsum);
  scan2_kernel<<<1, 64, 0, stream>>>(p0, p1, p2, bsum);
  scan3_kernel<<<nbtot, 256, 0, stream>>>(p0, p1, p2, bsum);

  fill_kernel<<<eb(E_rates), 256, 0, stream>>>(ei_rates, E_rates, cur_rates, es_rates);
  fill_kernel<<<eb(E_rev),   256, 0, stream>>>(ei_rev,   E_rev,   cur_rev,   es_rev);
  fill_kernel<<<eb(E_fol),   256, 0, stream>>>(ei_fol,   E_fol,   cur_fol,   es_fol);

  gather_kernel<<<(NI + 3) / 4, 256, 0, stream>>>(xb_user, rp_rates, es_rates, mean_rates, NI);
  gather_kernel<<<(NU + 3) / 4, 256, 0, stream>>>(xb_item, rp_rev,   es_rev,   mean_rev,   NU);
  gather_kernel<<<(NU + 3) / 4, 256, 0, stream>>>(xb_user, rp_fol,   es_fol,   mean_fol,   NU);

  // out_user = [mean_rev | mean_fol | xb_user] @ Wb_user^T + b_user  (K=384)
  BSrcs su; su.s[0] = mean_rev; su.s[1] = mean_fol; su.s[2] = xb_user;
  gemm_kernel<<<(NU + 63) / 64, 256, 0, stream>>>(su, Wb_user, 384, b_user,
                                                  (float*)d_out, NU);
  // out_item = [mean_rates | xb_item] @ Wb_item^T + b_item           (K=256)
  BSrcs si; si.s[0] = mean_rates; si.s[1] = xb_item; si.s[2] = nullptr;
  gemm_kernel<<<(NI + 63) / 64, 256, 0, stream>>>(si, Wb_item, 256, b_item,
                                                  (float*)d_out + (size_t)NU * D, NI);
}

// Round 5
// 460.221 us; speedup vs baseline: 2.9839x; 1.2044x over previous
//
#include <hip/hip_runtime.h>

#define D 128
#define SCHUNK 4096

typedef __attribute__((ext_vector_type(8))) short bf16x8;
typedef __attribute__((ext_vector_type(4))) float f32x4;

__device__ inline unsigned short f2bf(float f) {
  unsigned u = __builtin_bit_cast(unsigned, f);
  unsigned r = u + 0x7FFFu + ((u >> 16) & 1u);
  return (unsigned short)(r >> 16);
}
__device__ inline float bf2f(unsigned short b) {
  unsigned u = ((unsigned)b) << 16;
  return __builtin_bit_cast(float, u);
}

// ---------------- fp32 -> bf16 conversion, both tables in one launch ------
__global__ void __launch_bounds__(256) conv2_kernel(
    const float* __restrict__ xu, const float* __restrict__ xi,
    unsigned short* __restrict__ xbu, unsigned short* __restrict__ xbi,
    int n4u, int n4i) {
  int i = blockIdx.x * 256 + threadIdx.x;
  const float* x;
  unsigned short* xb;
  if (i < n4u) { x = xu; xb = xbu; }
  else { i -= n4u; if (i >= n4i) return; x = xi; xb = xbi; }
  float4 v = ((const float4*)x)[i];
  ushort4 o;
  o.x = f2bf(v.x); o.y = f2bf(v.y); o.z = f2bf(v.z); o.w = f2bf(v.w);
  ((ushort4*)xb)[i] = o;
}

// ---------------- histogram of dst, 3 relations in one launch -------------
struct EdgeArgs {
  const int* ei[3];
  int* cnt[3];      // hist: counts
  int* cur[3];      // fill: cursors
  int* es[3];       // fill: output src list
  int ne[3];
  int nb[3];
};

__global__ void __launch_bounds__(256) hist3_kernel(EdgeArgs H) {
  int b = blockIdx.x, rel = 0;
  while (b >= H.nb[rel]) { b -= H.nb[rel]; rel++; }
  int i = b * 256 + threadIdx.x;
  if (i < H.ne[rel]) atomicAdd(&H.cnt[rel][H.ei[rel][H.ne[rel] + i]], 1);
}

__global__ void __launch_bounds__(256) fill3_kernel(EdgeArgs H) {
  int b = blockIdx.x, rel = 0;
  while (b >= H.nb[rel]) { b -= H.nb[rel]; rel++; }
  int i = b * 256 + threadIdx.x;
  if (i < H.ne[rel]) {
    int pos = atomicAdd(&H.cur[rel][H.ei[rel][H.ne[rel] + i]], 1);
    H.es[rel][pos] = H.ei[rel][i];
  }
}

// ---------------- hierarchical exclusive scan over 3 relations ----------
struct ScanP { const int* c; int* r; int* u; int n; int nb; };

__device__ inline ScanP pick_rel(int& b, ScanP p0, ScanP p1, ScanP p2) {
  if (b < p0.nb) return p0;
  b -= p0.nb;
  if (b < p1.nb) return p1;
  b -= p1.nb;
  return p2;
}

__global__ void __launch_bounds__(256) scan1_kernel(ScanP p0, ScanP p1, ScanP p2,
                                                    int* __restrict__ bsum) {
  int b = blockIdx.x;
  ScanP p = pick_rel(b, p0, p1, p2);
  const int tid = threadIdx.x;
  const int base = b * SCHUNK + tid * 16;
  int s = 0;
#pragma unroll
  for (int v = 0; v < 4; v++) {
    int idx = base + v * 4;
    if (idx + 3 < p.n) {
      int4 t = *(const int4*)(p.c + idx);
      s += t.x + t.y + t.z + t.w;
    } else {
#pragma unroll
      for (int e = 0; e < 4; e++)
        if (idx + e < p.n) s += p.c[idx + e];
    }
  }
  __shared__ int red[256];
  red[tid] = s;
  __syncthreads();
  for (int off = 128; off > 0; off >>= 1) {
    if (tid < off) red[tid] += red[tid + off];
    __syncthreads();
  }
  if (tid == 0) bsum[blockIdx.x] = red[0];
}

__global__ void scan2_kernel(ScanP p0, ScanP p1, ScanP p2, int* __restrict__ bsum) {
  int t = threadIdx.x;
  if (t >= 3) return;
  ScanP p = (t == 0) ? p0 : (t == 1) ? p1 : p2;
  int boff = (t == 0) ? 0 : (t == 1) ? p0.nb : p0.nb + p1.nb;
  int run = 0;
  for (int i = 0; i < p.nb; i++) {
    int v = bsum[boff + i];
    bsum[boff + i] = run;
    run += v;
  }
  p.r[p.n] = run;
}

__global__ void __launch_bounds__(256) scan3_kernel(ScanP p0, ScanP p1, ScanP p2,
                                                    const int* __restrict__ bsum) {
  int b = blockIdx.x;
  ScanP p = pick_rel(b, p0, p1, p2);
  const int tid = threadIdx.x;
  const int base = b * SCHUNK + tid * 16;
  int vals[16];
  int s = 0;
#pragma unroll
  for (int v = 0; v < 4; v++) {
    int idx = base + v * 4;
    int4 t = {0, 0, 0, 0};
    if (idx + 3 < p.n) {
      t = *(const int4*)(p.c + idx);
    } else {
      if (idx + 0 < p.n) t.x = p.c[idx + 0];
      if (idx + 1 < p.n) t.y = p.c[idx + 1];
      if (idx + 2 < p.n) t.z = p.c[idx + 2];
      if (idx + 3 < p.n) t.w = p.c[idx + 3];
    }
    vals[v * 4 + 0] = t.x; vals[v * 4 + 1] = t.y;
    vals[v * 4 + 2] = t.z; vals[v * 4 + 3] = t.w;
    s += t.x + t.y + t.z + t.w;
  }
  __shared__ int buf[256];
  buf[tid] = s;
  __syncthreads();
  for (int off = 1; off < 256; off <<= 1) {
    int t = (tid >= off) ? buf[tid - off] : 0;
    __syncthreads();
    buf[tid] += t;
    __syncthreads();
  }
  int run = buf[tid] - s + bsum[blockIdx.x];
#pragma unroll
  for (int v = 0; v < 16; v++) {
    int idx = base + v;
    if (idx < p.n) { p.r[idx] = run; p.u[idx] = run; }
    run += vals[v];
  }
}

// ------- gather + mean, 3 relations, one wave/row, 4-way unrolled ---------
struct GatherArgs {
  const unsigned short* xb[3];
  const int* rp[3];
  const int* es[3];
  unsigned short* mean[3];
  int m[3];
  int nb[3];
};

__global__ void __launch_bounds__(256) gather3_kernel(GatherArgs G) {
  int b = blockIdx.x, rel = 0;
  while (b >= G.nb[rel]) { b -= G.nb[rel]; rel++; }
  int row = b * 4 + (threadIdx.x >> 6);
  if (row >= G.m[rel]) return;
  const int lane = threadIdx.x & 63;
  const unsigned short* __restrict__ xb = G.xb[rel];
  const int* __restrict__ rowptr = G.rp[rel];
  const int* __restrict__ esrc = G.es[rel];
  const int beg = rowptr[row], end = rowptr[row + 1];
  const size_t loff = lane * 2;
  float a0 = 0.f, a1 = 0.f, b0 = 0.f, b1 = 0.f;
  float c0 = 0.f, c1 = 0.f, d0 = 0.f, d1 = 0.f;
  int j = beg;
  for (; j + 4 <= end; j += 4) {
    int s0 = esrc[j], s1 = esrc[j + 1], s2 = esrc[j + 2], s3 = esrc[j + 3];
    unsigned v0 = *(const unsigned*)(xb + (size_t)s0 * D + loff);
    unsigned v1 = *(const unsigned*)(xb + (size_t)s1 * D + loff);
    unsigned v2 = *(const unsigned*)(xb + (size_t)s2 * D + loff);
    unsigned v3 = *(const unsigned*)(xb + (size_t)s3 * D + loff);
    a0 += bf2f((unsigned short)(v0 & 0xFFFFu)); a1 += bf2f((unsigned short)(v0 >> 16));
    b0 += bf2f((unsigned short)(v1 & 0xFFFFu)); b1 += bf2f((unsigned short)(v1 >> 16));
    c0 += bf2f((unsigned short)(v2 & 0xFFFFu)); c1 += bf2f((unsigned short)(v2 >> 16));
    d0 += bf2f((unsigned short)(v3 & 0xFFFFu)); d1 += bf2f((unsigned short)(v3 >> 16));
  }
  for (; j < end; j++) {
    int s = esrc[j];
    unsigned v = *(const unsigned*)(xb + (size_t)s * D + loff);
    a0 += bf2f((unsigned short)(v & 0xFFFFu)); a1 += bf2f((unsigned short)(v >> 16));
  }
  a0 += (b0 + c0) + d0;
  a1 += (b1 + c1) + d1;
  float inv = 1.0f / (float)max(end - beg, 1);
  unsigned o = (unsigned)f2bf(a0 * inv) | ((unsigned)f2bf(a1 * inv) << 16);
  *(unsigned*)(G.mean[rel] + (size_t)row * D + loff) = o;
}

// ---------------- prep: combined bf16 weights (n-major) + biases ----------
__global__ void __launch_bounds__(384) prep_kernel(
    const float* __restrict__ Wl_rates, const float* __restrict__ Wr_rates, const float* __restrict__ bl_rates,
    const float* __restrict__ Wl_rev, const float* __restrict__ Wr_rev, const float* __restrict__ bl_rev,
    const float* __restrict__ Wl_fol, const float* __restrict__ Wr_fol, const float* __restrict__ bl_fol,
    unsigned short* __restrict__ Wb_user, unsigned short* __restrict__ Wb_item,
    float* __restrict__ b_user, float* __restrict__ b_item) {
  int n = blockIdx.x;          // 0..127
  int k = threadIdx.x;         // 0..383
  float v;
  if (k < 128)      v = 0.5f * Wl_rev[n * 128 + k];
  else if (k < 256) v = 0.5f * Wl_fol[n * 128 + (k - 128)];
  else              v = 0.5f * (Wr_rev[n * 128 + (k - 256)] + Wr_fol[n * 128 + (k - 256)]);
  Wb_user[n * 384 + k] = f2bf(v);
  if (k < 256) {
    float w = (k < 128) ? Wl_rates[n * 128 + k] : Wr_rates[n * 128 + (k - 128)];
    Wb_item[n * 256 + k] = f2bf(w);
  }
  if (n == 0 && k < 128) {
    b_item[k] = bl_rates[k];
    b_user[k] = 0.5f * (bl_rev[k] + bl_fol[k]);
  }
}

// ---------------- bf16 MFMA GEMM, both outputs in one launch --------------
struct BSrcs { const unsigned short* s[3]; };
struct GemmArgs {
  BSrcs su, si;
  const unsigned short* wbU; const unsigned short* wbI;
  const float* bU; const float* bI;
  float* outU; float* outI;
  int MU, MI, nbU;
};

__global__ void __launch_bounds__(256) gemm2_kernel(GemmArgs A) {
  const bool isU = (int)blockIdx.x < A.nbU;
  const int bid = isU ? blockIdx.x : blockIdx.x - A.nbU;
  const BSrcs S = isU ? A.su : A.si;
  const unsigned short* __restrict__ Wb = isU ? A.wbU : A.wbI;
  const int K = isU ? 384 : 256;
  const float* __restrict__ bias = isU ? A.bU : A.bI;
  float* __restrict__ out = isU ? A.outU : A.outI;
  const int M = isU ? A.MU : A.MI;

  __shared__ __align__(16) unsigned short As[64][72];
  __shared__ __align__(16) unsigned short Ws[128][72];
  const int tid = threadIdx.x;
  const int lane = tid & 63;
  const int wave = tid >> 6;
  const int wrow = (wave >> 1) * 32;
  const int wcol = (wave & 1) * 64;
  const int l15 = lane & 15;
  const int quad = lane >> 4;
  const int m0 = bid * 64;

  f32x4 acc[2][4];
#pragma unroll
  for (int r = 0; r < 2; r++)
#pragma unroll
    for (int c = 0; c < 4; c++) acc[r][c] = (f32x4){0.f, 0.f, 0.f, 0.f};

  const int nchunks = K >> 6;
  for (int ch = 0; ch < nchunks; ch++) {
    const unsigned short* sp = S.s[ch >> 1];
    const int coff = (ch & 1) << 6;
    {
      int row = tid >> 2, part = tid & 3;
      int m = m0 + row;
      uint4 v0 = {0, 0, 0, 0}, v1 = {0, 0, 0, 0};
      if (m < M) {
        const uint4* g = (const uint4*)(sp + (size_t)m * D + coff + part * 16);
        v0 = g[0]; v1 = g[1];
      }
      uint4* l = (uint4*)(&As[row][part * 16]);
      l[0] = v0; l[1] = v1;
    }
    {
      int n = tid >> 1, half = tid & 1;
      const uint4* g = (const uint4*)(Wb + (size_t)n * K + ch * 64 + half * 32);
      uint4* l = (uint4*)(&Ws[n][half * 32]);
      l[0] = g[0]; l[1] = g[1]; l[2] = g[2]; l[3] = g[3];
    }
    __syncthreads();
#pragma unroll
    for (int kk = 0; kk < 64; kk += 32) {
      const int kb = kk + quad * 8;
      bf16x8 a0 = *(const bf16x8*)&As[wrow + l15][kb];
      bf16x8 a1 = *(const bf16x8*)&As[wrow + 16 + l15][kb];
      bf16x8 b0 = *(const bf16x8*)&Ws[wcol + l15][kb];
      bf16x8 b1 = *(const bf16x8*)&Ws[wcol + 16 + l15][kb];
      bf16x8 b2 = *(const bf16x8*)&Ws[wcol + 32 + l15][kb];
      bf16x8 b3 = *(const bf16x8*)&Ws[wcol + 48 + l15][kb];
      acc[0][0] = __builtin_amdgcn_mfma_f32_16x16x32_bf16(a0, b0, acc[0][0], 0, 0, 0);
      acc[0][1] = __builtin_amdgcn_mfma_f32_16x16x32_bf16(a0, b1, acc[0][1], 0, 0, 0);
      acc[0][2] = __builtin_amdgcn_mfma_f32_16x16x32_bf16(a0, b2, acc[0][2], 0, 0, 0);
      acc[0][3] = __builtin_amdgcn_mfma_f32_16x16x32_bf16(a0, b3, acc[0][3], 0, 0, 0);
      acc[1][0] = __builtin_amdgcn_mfma_f32_16x16x32_bf16(a1, b0, acc[1][0], 0, 0, 0);
      acc[1][1] = __builtin_amdgcn_mfma_f32_16x16x32_bf16(a1, b1, acc[1][1], 0, 0, 0);
      acc[1][2] = __builtin_amdgcn_mfma_f32_16x16x32_bf16(a1, b2, acc[1][2], 0, 0, 0);
      acc[1][3] = __builtin_amdgcn_mfma_f32_16x16x32_bf16(a1, b3, acc[1][3], 0, 0, 0);
    }
    __syncthreads();
  }
#pragma unroll
  for (int c = 0; c < 4; c++) {
    const int n = wcol + c * 16 + l15;
    const float bv = bias[n];
#pragma unroll
    for (int r = 0; r < 2; r++) {
      const int mrow = m0 + wrow + r * 16 + quad * 4;
#pragma unroll
      for (int i = 0; i < 4; i++) {
        if (mrow + i < M) out[(size_t)(mrow + i) * D + n] = acc[r][c][i] + bv;
      }
    }
  }
}

extern "C" void kernel_launch(void* const* d_in, const int* in_sizes, int n_in,
                              void* d_out, int out_size, void* d_ws, size_t ws_size,
                              hipStream_t stream) {
  const float* x_user   = (const float*)d_in[0];
  const float* x_item   = (const float*)d_in[1];
  const int*   ei_rates = (const int*)d_in[2];
  const int*   ei_rev   = (const int*)d_in[3];
  const int*   ei_fol   = (const int*)d_in[4];
  const float* Wl_rates = (const float*)d_in[5];
  const float* bl_rates = (const float*)d_in[6];
  const float* Wr_rates = (const float*)d_in[7];
  const float* Wl_rev   = (const float*)d_in[8];
  const float* bl_rev   = (const float*)d_in[9];
  const float* Wr_rev   = (const float*)d_in[10];
  const float* Wl_fol   = (const float*)d_in[11];
  const float* bl_fol   = (const float*)d_in[12];
  const float* Wr_fol   = (const float*)d_in[13];

  const int NU = in_sizes[0] / D;       // 50000
  const int NI = in_sizes[1] / D;       // 50000
  const int E_rates = in_sizes[2] / 2;
  const int E_rev   = in_sizes[3] / 2;
  const int E_fol   = in_sizes[4] / 2;

  // ---- workspace carve-up (byte-based, 16B aligned) ----
  char* wsb = (char*)d_ws;
  size_t off = 0;
  auto take = [&](size_t bytes) {
    char* p = wsb + off;
    off += (bytes + 15) & ~(size_t)15;
    return p;
  };
  int* cnt_rates = (int*)take((size_t)NI * 4);
  int* cnt_rev   = (int*)take((size_t)NU * 4);
  int* cnt_fol   = (int*)take((size_t)NU * 4);
  const size_t cnt_bytes = off;          // region to zero
  int* rp_rates  = (int*)take((size_t)(NI + 1) * 4);
  int* rp_rev    = (int*)take((size_t)(NU + 1) * 4);
  int* rp_fol    = (int*)take((size_t)(NU + 1) * 4);
  int* cur_rates = (int*)take((size_t)NI * 4);
  int* cur_rev   = (int*)take((size_t)NU * 4);
  int* cur_fol   = (int*)take((size_t)NU * 4);
  int* es_rates  = (int*)take((size_t)E_rates * 4);
  int* es_rev    = (int*)take((size_t)E_rev * 4);
  int* es_fol    = (int*)take((size_t)E_fol * 4);
  int* bsum      = (int*)take(256 * 4);
  unsigned short* xb_user    = (unsigned short*)take((size_t)NU * D * 2);
  unsigned short* xb_item    = (unsigned short*)take((size_t)NI * D * 2);
  unsigned short* mean_rates = (unsigned short*)take((size_t)NI * D * 2);
  unsigned short* mean_rev   = (unsigned short*)take((size_t)NU * D * 2);
  unsigned short* mean_fol   = (unsigned short*)take((size_t)NU * D * 2);
  unsigned short* Wb_user    = (unsigned short*)take(128 * 384 * 2);
  unsigned short* Wb_item    = (unsigned short*)take(128 * 256 * 2);
  float* b_user = (float*)take(128 * 4);
  float* b_item = (float*)take(128 * 4);

  hipMemsetAsync(d_ws, 0, cnt_bytes, stream);
  prep_kernel<<<128, 384, 0, stream>>>(Wl_rates, Wr_rates, bl_rates,
                                       Wl_rev, Wr_rev, bl_rev,
                                       Wl_fol, Wr_fol, bl_fol,
                                       Wb_user, Wb_item, b_user, b_item);
  {
    int n4u = NU * D / 4, n4i = NI * D / 4;
    conv2_kernel<<<(n4u + n4i + 255) / 256, 256, 0, stream>>>(
        x_user, x_item, xb_user, xb_item, n4u, n4i);
  }

  auto eb = [](int e) { return (e + 255) / 256; };
  EdgeArgs ea;
  ea.ei[0] = ei_rates; ea.cnt[0] = cnt_rates; ea.cur[0] = cur_rates; ea.es[0] = es_rates;
  ea.ne[0] = E_rates;  ea.nb[0] = eb(E_rates);
  ea.ei[1] = ei_rev;   ea.cnt[1] = cnt_rev;   ea.cur[1] = cur_rev;   ea.es[1] = es_rev;
  ea.ne[1] = E_rev;    ea.nb[1] = eb(E_rev);
  ea.ei[2] = ei_fol;   ea.cnt[2] = cnt_fol;   ea.cur[2] = cur_fol;   ea.es[2] = es_fol;
  ea.ne[2] = E_fol;    ea.nb[2] = eb(E_fol);
  const int enb = ea.nb[0] + ea.nb[1] + ea.nb[2];
  hist3_kernel<<<enb, 256, 0, stream>>>(ea);

  auto nb = [](int n) { return (n + SCHUNK - 1) / SCHUNK; };
  ScanP p0{cnt_rates, rp_rates, cur_rates, NI, nb(NI)};
  ScanP p1{cnt_rev,   rp_rev,   cur_rev,   NU, nb(NU)};
  ScanP p2{cnt_fol,   rp_fol,   cur_fol,   NU, nb(NU)};
  const int nbtot = p0.nb + p1.nb + p2.nb;
  scan1_kernel<<<nbtot, 256, 0, stream>>>(p0, p1, p2, bsum);
  scan2_kernel<<<1, 64, 0, stream>>>(p0, p1, p2, bsum);
  scan3_kernel<<<nbtot, 256, 0, stream>>>(p0, p1, p2, bsum);

  fill3_kernel<<<enb, 256, 0, stream>>>(ea);

  GatherArgs ga;
  ga.xb[0] = xb_user; ga.rp[0] = rp_rates; ga.es[0] = es_rates; ga.mean[0] = mean_rates;
  ga.m[0] = NI; ga.nb[0] = (NI + 3) / 4;
  ga.xb[1] = xb_item; ga.rp[1] = rp_rev;   ga.es[1] = es_rev;   ga.mean[1] = mean_rev;
  ga.m[1] = NU; ga.nb[1] = (NU + 3) / 4;
  ga.xb[2] = xb_user; ga.rp[2] = rp_fol;   ga.es[2] = es_fol;   ga.mean[2] = mean_fol;
  ga.m[2] = NU; ga.nb[2] = (NU + 3) / 4;
  gather3_kernel<<<ga.nb[0] + ga.nb[1] + ga.nb[2], 256, 0, stream>>>(ga);

  GemmArgs gma;
  gma.su.s[0] = mean_rev;   gma.su.s[1] = mean_fol; gma.su.s[2] = xb_user;
  gma.si.s[0] = mean_rates; gma.si.s[1] = xb_item;  gma.si.s[2] = nullptr;
  gma.wbU = Wb_user; gma.wbI = Wb_item;
  gma.bU = b_user;   gma.bI = b_item;
  gma.outU = (float*)d_out;
  gma.outI = (float*)d_out + (size_t)NU * D;
  gma.MU = NU; gma.MI = NI;
  gma.nbU = (NU + 63) / 64;
  const int nbI = (NI + 63) / 64;
  gemm2_kernel<<<gma.nbU + nbI, 256, 0, stream>>>(gma);
}